// Round 3
// baseline (2873.530 us; speedup 1.0000x reference)
//
#include <hip/hip_runtime.h>
#include <stdint.h>

typedef __bf16 bf16;
typedef __attribute__((ext_vector_type(8))) __bf16 bf16x8;
typedef __attribute__((ext_vector_type(4))) float f32x4;

#define GRU_H 2048
#define ODIM 96
#define PADX 128
#define BATCH 1024
#define TSTEPS 25

__device__ __forceinline__ float sigm(float x) { return 1.f / (1.f + __expf(-x)); }

__device__ __forceinline__ void gload16(const void* g, void* l) {
  __builtin_amdgcn_global_load_lds((const __attribute__((address_space(1))) uint32_t*)g,
                                   (__attribute__((address_space(3))) uint32_t*)l, 16, 0, 0);
}

// ---------------- init / convert kernels ----------------
__global__ void k_cvt(const float* __restrict__ s, bf16* __restrict__ d, int n) {
  int stride = gridDim.x * blockDim.x;
  for (int i = blockIdx.x * blockDim.x + threadIdx.x; i < n; i += stride)
    d[i] = (bf16)s[i];
}

__global__ void k_cvt_pad(const float* __restrict__ s, bf16* __restrict__ d,
                          int rows, int cin, int cout) {
  int n = rows * cout;
  int stride = gridDim.x * blockDim.x;
  for (int i = blockIdx.x * blockDim.x + threadIdx.x; i < n; i += stride) {
    int r = i / cout, c = i - r * cout;
    d[i] = (c < cin) ? (bf16)s[r * cin + c] : (bf16)0.f;
  }
}

__global__ void k_init_h(const float* __restrict__ s, float* __restrict__ hf,
                         bf16* __restrict__ hb, int n) {
  int stride = gridDim.x * blockDim.x;
  for (int i = blockIdx.x * blockDim.x + threadIdx.x; i < n; i += stride) {
    float v = s[i];
    hf[i] = v;
    hb[i] = (bf16)v;
  }
}

// ---------------- fused GRU layer kernel ----------------
// Block: 256 threads = 4 waves, each wave owns 64 rows x 16 cols x 3 gates.
// Block tile: 64 batch-rows x 64 H-cols x 3 gates. grid = (H/64=32, BATCH/64=16)
// -> 512 blocks = 2 blocks/CU (LDS 64 KB/block). 2-buffer depth-1 pipeline,
// ONE fused vmcnt+lgkmcnt+barrier per K-step. LDS linear-write via
// global_load_lds, XOR-swizzle applied on the global source address (rule #21),
// involution re-applied on ds_read side.
__global__ __launch_bounds__(256) void k_gru(
    const bf16* __restrict__ xb, int kx,          // x input [1024][kx], kx = 128 or 2048
    const bf16* __restrict__ hb,                  // h_prev bf16 [1024][2048]
    const bf16* __restrict__ wih,                 // [3*2048][kx]
    const bf16* __restrict__ whh,                 // [3*2048][2048]
    const float* __restrict__ bih, const float* __restrict__ bhh,
    const float* __restrict__ hprevf,             // h_prev fp32 master
    float* __restrict__ hnewf, bf16* __restrict__ hnewb) {
  __shared__ alignas(16) char sm[2][32768];       // per buffer: A 8KB (64x64) + B 24KB (192x64)

  const int tid = threadIdx.x;
  const int l = tid & 63;
  const int wn = tid >> 6;                        // 4 waves = 4 col-slices of 16
  const int wb = tid & ~63;                       // wave-uniform lane-0 tid
  const int bn0 = blockIdx.x * 64;
  const int bm0 = blockIdx.y * 64;
  const int lm = l >> 4, ln = l & 15;
  char* sm0 = &sm[0][0];

  const int S1 = GRU_H / 64;                      // 32 hh steps
  const int S2 = kx / 64;                         // 2 or 32 ih steps

  f32x4 accR[4] = {};
  f32x4 accZ[4] = {};
  f32x4 accNH[4] = {};
  f32x4 accNI[4] = {};

  // stage one 64-wide K-slice: A rows [bm0,bm0+64), B rows 3 x [bn0,bn0+64)
  auto stage = [&](int lb2, const bf16* __restrict__ A, const bf16* __restrict__ W,
                   int K, int k0) {
    char* sb = sm0 + lb2;
#pragma unroll
    for (int it = 0; it < 2; ++it) {              // A: 512 chunks of 16B
      int c = it * 256 + tid;
      int row = c >> 3, pos = c & 7, slot = pos ^ (row & 7);
      gload16(A + (size_t)(bm0 + row) * K + k0 + slot * 8,
              sb + ((it * 256 + wb) << 4));
    }
#pragma unroll
    for (int it = 0; it < 6; ++it) {              // B: 1536 chunks of 16B
      int c = it * 256 + tid;
      int row = c >> 3, pos = c & 7, slot = pos ^ (row & 7);
      int g = row >> 6, r = row & 63;
      gload16(W + (size_t)(g * GRU_H + bn0 + r) * K + k0 + slot * 8,
              sb + 8192 + ((it * 256 + wb) << 4));
    }
  };

  auto computeStep = [&](int lb2, f32x4 (&accN)[4]) {
    const char* bp = sm0 + lb2;
#pragma unroll
    for (int kf = 0; kf < 2; ++kf) {
      bf16x8 af[4];
#pragma unroll
      for (int mf = 0; mf < 4; ++mf) {
        int row = mf * 16 + ln;
        int pos = (kf * 4 + lm) ^ (row & 7);
        af[mf] = *(const bf16x8*)(bp + row * 128 + (pos << 4));
      }
#pragma unroll
      for (int g = 0; g < 3; ++g) {
        int row = g * 64 + wn * 16 + ln;
        int pos = (kf * 4 + lm) ^ (row & 7);
        bf16x8 bq = *(const bf16x8*)(bp + 8192 + row * 128 + (pos << 4));
        f32x4* accG = (g == 0) ? accR : (g == 1) ? accZ : accN;
#pragma unroll
        for (int mf = 0; mf < 4; ++mf)
          accG[mf] = __builtin_amdgcn_mfma_f32_16x16x32_bf16(af[mf], bq, accG[mf], 0, 0, 0);
      }
    }
  };

  // prologue
  stage(0, hb, whh, GRU_H, 0);
  asm volatile("s_waitcnt vmcnt(0)\ns_barrier" ::: "memory");

  int lb = 0;
  for (int s = 0; s < S1; ++s) {                  // hh phase
    if (s + 1 < S1) stage(lb ^ 32768, hb, whh, GRU_H, (s + 1) * 64);
    else            stage(lb ^ 32768, xb, wih, kx, 0);
    computeStep(lb, accNH);
    asm volatile("s_waitcnt vmcnt(0) lgkmcnt(0)\ns_barrier" ::: "memory");
    lb ^= 32768;
  }
  for (int s = 0; s < S2; ++s) {                  // ih phase
    if (s + 1 < S2) {
      stage(lb ^ 32768, xb, wih, kx, (s + 1) * 64);
      computeStep(lb, accNI);
      asm volatile("s_waitcnt vmcnt(0) lgkmcnt(0)\ns_barrier" ::: "memory");
      lb ^= 32768;
    } else {
      computeStep(lb, accNI);                     // last step: no stage, no sync
    }
  }

  // ---- GRU epilogue ----
  {
    int j = bn0 + wn * 16 + ln;
    float br = bih[j] + bhh[j];
    float bz = bih[GRU_H + j] + bhh[GRU_H + j];
    float bin = bih[2 * GRU_H + j];
    float bhn = bhh[2 * GRU_H + j];
#pragma unroll
    for (int mf = 0; mf < 4; ++mf) {
#pragma unroll
      for (int rr = 0; rr < 4; ++rr) {
        int m = bm0 + mf * 16 + lm * 4 + rr;
        size_t idx = (size_t)m * GRU_H + j;
        float hp = hprevf[idx];
        float rg = sigm(accR[mf][rr] + br);
        float zg = sigm(accZ[mf][rr] + bz);
        float ng = tanhf(accNI[mf][rr] + bin + rg * (accNH[mf][rr] + bhn));
        float hn = (1.f - zg) * ng + zg * hp;
        hnewf[idx] = hn;
        hnewb[idx] = (bf16)hn;
      }
    }
  }
}

// ---------------- FC (split-K) ----------------
// grid.x = 16 K-chunks of 128, grid.y = 16 M-tiles of 64. 256 thr = 4 waves.
__global__ __launch_bounds__(256, 1) void k_fc_part(const bf16* __restrict__ h1b,
                                                    const bf16* __restrict__ wfc,
                                                    float* __restrict__ part) {
  const int kc = blockIdx.x;
  const int mt = blockIdx.y;
  const int l = threadIdx.x & 63, w = threadIdx.x >> 6;
  const int lm = l >> 4, ln = l & 15;
  const int m0 = mt * 64 + w * 16;
  const int k0 = kc * 128;
  f32x4 acc[6] = {};
#pragma unroll
  for (int kf = 0; kf < 4; ++kf) {
    bf16x8 a = *(const bf16x8*)&h1b[(size_t)(m0 + ln) * GRU_H + k0 + kf * 32 + lm * 8];
#pragma unroll
    for (int nf = 0; nf < 6; ++nf) {
      bf16x8 b = *(const bf16x8*)&wfc[(size_t)(nf * 16 + ln) * GRU_H + k0 + kf * 32 + lm * 8];
      acc[nf] = __builtin_amdgcn_mfma_f32_16x16x32_bf16(a, b, acc[nf], 0, 0, 0);
    }
  }
  float* base = part + (size_t)kc * (BATCH * ODIM);
#pragma unroll
  for (int nf = 0; nf < 6; ++nf)
#pragma unroll
    for (int rr = 0; rr < 4; ++rr)
      base[(size_t)(m0 + lm * 4 + rr) * ODIM + nf * 16 + ln] = acc[nf][rr];
}

__global__ void k_fc_red(const float* __restrict__ part, const float* __restrict__ bfc,
                         float* __restrict__ dout, bf16* __restrict__ decb, int t) {
  int i = blockIdx.x * blockDim.x + threadIdx.x;
  if (i >= BATCH * ODIM) return;
  int m = i / ODIM, n = i - m * ODIM;
  float s = bfc[n];
#pragma unroll
  for (int kc = 0; kc < 16; ++kc) s += part[(size_t)kc * (BATCH * ODIM) + i];
  s = sigm(s);
  dout[(size_t)m * (TSTEPS * ODIM) + t * ODIM + n] = s;
  decb[m * PADX + n] = (bf16)s;
}

// ---------------- launch ----------------
extern "C" void kernel_launch(void* const* d_in, const int* in_sizes, int n_in,
                              void* d_out, int out_size, void* d_ws, size_t ws_size,
                              hipStream_t stream) {
  const float* input   = (const float*)d_in[0];
  const float* hiddens = (const float*)d_in[2];
  const float* W_ih0   = (const float*)d_in[3];
  const float* W_hh0   = (const float*)d_in[4];
  const float* b_ih0   = (const float*)d_in[5];
  const float* b_hh0   = (const float*)d_in[6];
  const float* W_ih1   = (const float*)d_in[7];
  const float* W_hh1   = (const float*)d_in[8];
  const float* b_ih1   = (const float*)d_in[9];
  const float* b_hh1   = (const float*)d_in[10];
  const float* W_fc    = (const float*)d_in[11];
  const float* b_fc    = (const float*)d_in[12];
  float* out = (float*)d_out;

  char* p = (char*)d_ws;
  auto take = [&](size_t n) { char* q = p; p += (n + 255) & ~(size_t)255; return q; };
  bf16* wih0b = (bf16*)take((size_t)3 * GRU_H * PADX * 2);
  bf16* whh0b = (bf16*)take((size_t)3 * GRU_H * GRU_H * 2);
  bf16* wih1b = (bf16*)take((size_t)3 * GRU_H * GRU_H * 2);
  bf16* whh1b = (bf16*)take((size_t)3 * GRU_H * GRU_H * 2);
  bf16* wfcb  = (bf16*)take((size_t)ODIM * GRU_H * 2);
  bf16* decb  = (bf16*)take((size_t)BATCH * PADX * 2);
  float* h0f[2], *h1f[2];
  bf16* h0b[2], *h1b[2];
  h0f[0] = (float*)take((size_t)BATCH * GRU_H * 4);
  h0f[1] = (float*)take((size_t)BATCH * GRU_H * 4);
  h1f[0] = (float*)take((size_t)BATCH * GRU_H * 4);
  h1f[1] = (float*)take((size_t)BATCH * GRU_H * 4);
  h0b[0] = (bf16*)take((size_t)BATCH * GRU_H * 2);
  h0b[1] = (bf16*)take((size_t)BATCH * GRU_H * 2);
  h1b[0] = (bf16*)take((size_t)BATCH * GRU_H * 2);
  h1b[1] = (bf16*)take((size_t)BATCH * GRU_H * 2);
  float* fcpart = (float*)take((size_t)16 * BATCH * ODIM * 4);

  // one-time (per launch) conversions
  k_cvt_pad<<<768, 256, 0, stream>>>(W_ih0, wih0b, 3 * GRU_H, ODIM, PADX);
  k_cvt<<<2048, 256, 0, stream>>>(W_hh0, whh0b, 3 * GRU_H * GRU_H);
  k_cvt<<<2048, 256, 0, stream>>>(W_ih1, wih1b, 3 * GRU_H * GRU_H);
  k_cvt<<<2048, 256, 0, stream>>>(W_hh1, whh1b, 3 * GRU_H * GRU_H);
  k_cvt<<<192, 256, 0, stream>>>(W_fc, wfcb, ODIM * GRU_H);
  k_cvt_pad<<<512, 256, 0, stream>>>(input, decb, BATCH, ODIM, PADX);
  k_init_h<<<2048, 256, 0, stream>>>(hiddens, h0f[0], h0b[0], BATCH * GRU_H);
  k_init_h<<<2048, 256, 0, stream>>>(hiddens + (size_t)BATCH * GRU_H, h1f[0], h1b[0], BATCH * GRU_H);

  int cur = 0;
  for (int t = 0; t < TSTEPS; ++t) {
    int nxt = cur ^ 1;
    k_gru<<<dim3(32, 16), 256, 0, stream>>>(decb, PADX, h0b[cur], wih0b, whh0b,
                                            b_ih0, b_hh0, h0f[cur], h0f[nxt], h0b[nxt]);
    k_gru<<<dim3(32, 16), 256, 0, stream>>>(h0b[nxt], GRU_H, h1b[cur], wih1b, whh1b,
                                            b_ih1, b_hh1, h1f[cur], h1f[nxt], h1b[nxt]);
    k_fc_part<<<dim3(16, 16), 256, 0, stream>>>(h1b[nxt], wfcb, fcpart);
    k_fc_red<<<384, 256, 0, stream>>>(fcpart, b_fc, out, decb, t);
    cur = nxt;
  }
}

// Round 4
// 2565.732 us; speedup vs baseline: 1.1200x; 1.1200x over previous
//
#include <hip/hip_runtime.h>
#include <stdint.h>

typedef __bf16 bf16;
typedef __attribute__((ext_vector_type(8))) __bf16 bf16x8;
typedef __attribute__((ext_vector_type(4))) float f32x4;

#define GRU_H 2048
#define ODIM 96
#define PADX 128
#define BATCH 1024
#define TSTEPS 25

__device__ __forceinline__ float sigm(float x) { return 1.f / (1.f + __expf(-x)); }

__device__ __forceinline__ void gload16(const void* g, void* l) {
  __builtin_amdgcn_global_load_lds((const __attribute__((address_space(1))) uint32_t*)g,
                                   (__attribute__((address_space(3))) uint32_t*)l, 16, 0, 0);
}

// ---------------- init / convert kernels ----------------
__global__ void k_cvt(const float* __restrict__ s, bf16* __restrict__ d, int n) {
  int stride = gridDim.x * blockDim.x;
  for (int i = blockIdx.x * blockDim.x + threadIdx.x; i < n; i += stride)
    d[i] = (bf16)s[i];
}

__global__ void k_cvt_pad(const float* __restrict__ s, bf16* __restrict__ d,
                          int rows, int cin, int cout) {
  int n = rows * cout;
  int stride = gridDim.x * blockDim.x;
  for (int i = blockIdx.x * blockDim.x + threadIdx.x; i < n; i += stride) {
    int r = i / cout, c = i - r * cout;
    d[i] = (c < cin) ? (bf16)s[r * cin + c] : (bf16)0.f;
  }
}

__global__ void k_init_h(const float* __restrict__ s, float* __restrict__ hf,
                         bf16* __restrict__ hb, int n) {
  int stride = gridDim.x * blockDim.x;
  for (int i = blockIdx.x * blockDim.x + threadIdx.x; i < n; i += stride) {
    float v = s[i];
    hf[i] = v;
    hb[i] = (bf16)v;
  }
}

// ---------------- fused GRU layer kernel ----------------
// 512 thr = 8 waves (wm = w&1 row-half, wn = w>>1 col-quarter).
// Block tile: 128 batch-rows x 64 H-cols x 3 gates; per wave 64 rows x 16 cols x 3.
// grid (32, 8) = 256 blocks = 1 block/CU (LDS 120 KB).
// Pipeline: 3 buffers, prefetch depth 2, ONE fused wait+barrier per K-step with
// counted vmcnt(5) (one stage in flight, never drained to 0 mid-loop).
// Stage issued AFTER the barrier; per-wave lgkmcnt(0) in the fused wait makes the
// 3-buffer write-after-read rotation safe. Loop unrolled x3 -> static buffers.
__global__ __launch_bounds__(512, 1) void k_gru(
    const bf16* __restrict__ xb, int kx,          // x input [1024][kx], kx = 128 or 2048
    const bf16* __restrict__ hb,                  // h_prev bf16 [1024][2048]
    const bf16* __restrict__ wih,                 // [3*2048][kx]
    const bf16* __restrict__ whh,                 // [3*2048][2048]
    const float* __restrict__ bih, const float* __restrict__ bhh,
    const float* __restrict__ hprevf,             // h_prev fp32 master
    float* __restrict__ hnewf, bf16* __restrict__ hnewb) {
  __shared__ alignas(16) char sm[3][40960];       // per buffer: A 16KB (128x64) + B 24KB (192x64)

  const int tid = threadIdx.x;
  const int l = tid & 63;
  const int w = tid >> 6;
  const int wm = w & 1, wn = w >> 1;              // wm: row half, wn: 16-col slice
  const int wb = tid & ~63;
  const int bn0 = blockIdx.x * 64;
  const int bm0 = blockIdx.y * 128;
  const int lm = l >> 4, ln = l & 15;
  char* sm0 = &sm[0][0];

  const int S1 = GRU_H / 64;                      // 32 hh steps
  const int S2 = kx / 64;                         // 2 or 32 ih steps
  const int S = S1 + S2;                          // 34 or 64; (S-1) % 3 == 0

  f32x4 accR[4] = {};
  f32x4 accZ[4] = {};
  f32x4 accNH[4] = {};
  f32x4 accNI[4] = {};

  // per-thread staging bases (phase-specific), LDS offsets are linear chunk order
  const bf16* pAhh[2]; const bf16* pAih[2]; int ldsA[2];
  const bf16* pWhh[3]; const bf16* pWih[3]; int ldsB[3];
#pragma unroll
  for (int i = 0; i < 2; ++i) {
    int c = i * 512 + tid, row = c >> 3, slot = (c & 7) ^ (row & 7);
    pAhh[i] = hb + (size_t)(bm0 + row) * GRU_H + slot * 8;
    pAih[i] = xb + (size_t)(bm0 + row) * kx + slot * 8;
    ldsA[i] = (i * 512 + wb) << 4;
  }
#pragma unroll
  for (int i = 0; i < 3; ++i) {
    int c = i * 512 + tid, row = c >> 3, slot = (c & 7) ^ (row & 7);
    int g = row >> 6, r = row & 63;
    pWhh[i] = whh + (size_t)(g * GRU_H + bn0 + r) * GRU_H + slot * 8;
    pWih[i] = wih + (size_t)(g * GRU_H + bn0 + r) * kx + slot * 8;
    ldsB[i] = 16384 + ((i * 512 + wb) << 4);
  }

  auto stageP = [&](const bf16* const (&pa)[2], const bf16* const (&pw)[3],
                    int koff, char* sb) {
#pragma unroll
    for (int i = 0; i < 2; ++i) gload16(pa[i] + koff, sb + ldsA[i]);
#pragma unroll
    for (int i = 0; i < 3; ++i) gload16(pw[i] + koff, sb + ldsB[i]);
  };
  auto stageSel = [&](int sp, char* sb) {
    if (sp < S1) stageP(pAhh, pWhh, sp * 64, sb);
    else         stageP(pAih, pWih, (sp - S1) * 64, sb);
  };

  auto computeStep = [&](const char* bp, f32x4 (&accN)[4]) {
#pragma unroll
    for (int kf = 0; kf < 2; ++kf) {
      bf16x8 af[4];
#pragma unroll
      for (int mf = 0; mf < 4; ++mf) {
        int row = wm * 64 + mf * 16 + ln;
        int pos = (kf * 4 + lm) ^ (row & 7);
        af[mf] = *(const bf16x8*)(bp + row * 128 + (pos << 4));
      }
#pragma unroll
      for (int g = 0; g < 3; ++g) {
        int row = g * 64 + wn * 16 + ln;
        int pos = (kf * 4 + lm) ^ (row & 7);
        bf16x8 bq = *(const bf16x8*)(bp + 16384 + row * 128 + (pos << 4));
        f32x4* accG = (g == 0) ? accR : (g == 1) ? accZ : accN;
#pragma unroll
        for (int mf = 0; mf < 4; ++mf)
          accG[mf] = __builtin_amdgcn_mfma_f32_16x16x32_bf16(af[mf], bq, accG[mf], 0, 0, 0);
      }
    }
  };

  auto body = [&](int s, char* bufR, char* bufW) {
    // vmcnt(5): stage(s+1)'s 5 loads may stay in flight; stage(s) must be done.
    // lgkmcnt(0): my ds_reads of buf[(s-1)%3] are complete -> bufW overwrite safe.
    asm volatile("s_waitcnt vmcnt(5) lgkmcnt(0)\ns_barrier" ::: "memory");
    if (s + 2 < S) stageSel(s + 2, bufW);
    __builtin_amdgcn_s_setprio(1);
    if (s < S1) computeStep(bufR, accNH);
    else        computeStep(bufR, accNI);
    __builtin_amdgcn_s_setprio(0);
  };

  // prologue: fill 2 deep
  stageSel(0, sm0);
  stageSel(1, sm0 + 40960);

  const int SM1 = S - 1;                          // 33 or 63, divisible by 3
  for (int s = 0; s < SM1; s += 3) {
    body(s + 0, sm0,         sm0 + 81920);
    body(s + 1, sm0 + 40960, sm0);
    body(s + 2, sm0 + 81920, sm0 + 40960);
  }
  // tail step SM1 (always in ih phase): buffer SM1 % 3 == 0
  asm volatile("s_waitcnt vmcnt(0) lgkmcnt(0)\ns_barrier" ::: "memory");
  __builtin_amdgcn_s_setprio(1);
  computeStep(sm0, accNI);
  __builtin_amdgcn_s_setprio(0);

  // ---- GRU epilogue ----
  {
    int j = bn0 + wn * 16 + ln;
    float br = bih[j] + bhh[j];
    float bz = bih[GRU_H + j] + bhh[GRU_H + j];
    float bin = bih[2 * GRU_H + j];
    float bhn = bhh[2 * GRU_H + j];
#pragma unroll
    for (int mf = 0; mf < 4; ++mf) {
#pragma unroll
      for (int rr = 0; rr < 4; ++rr) {
        int m = bm0 + wm * 64 + mf * 16 + lm * 4 + rr;
        size_t idx = (size_t)m * GRU_H + j;
        float hp = hprevf[idx];
        float rg = sigm(accR[mf][rr] + br);
        float zg = sigm(accZ[mf][rr] + bz);
        float ng = tanhf(accNI[mf][rr] + bin + rg * (accNH[mf][rr] + bhn));
        float hn = (1.f - zg) * ng + zg * hp;
        hnewf[idx] = hn;
        hnewb[idx] = (bf16)hn;
      }
    }
  }
}

// ---------------- FC (split-K) ----------------
// grid.x = 16 K-chunks of 128, grid.y = 16 M-tiles of 64. 256 thr = 4 waves.
__global__ __launch_bounds__(256, 1) void k_fc_part(const bf16* __restrict__ h1b,
                                                    const bf16* __restrict__ wfc,
                                                    float* __restrict__ part) {
  const int kc = blockIdx.x;
  const int mt = blockIdx.y;
  const int l = threadIdx.x & 63, w = threadIdx.x >> 6;
  const int lm = l >> 4, ln = l & 15;
  const int m0 = mt * 64 + w * 16;
  const int k0 = kc * 128;
  f32x4 acc[6] = {};
#pragma unroll
  for (int kf = 0; kf < 4; ++kf) {
    bf16x8 a = *(const bf16x8*)&h1b[(size_t)(m0 + ln) * GRU_H + k0 + kf * 32 + lm * 8];
#pragma unroll
    for (int nf = 0; nf < 6; ++nf) {
      bf16x8 b = *(const bf16x8*)&wfc[(size_t)(nf * 16 + ln) * GRU_H + k0 + kf * 32 + lm * 8];
      acc[nf] = __builtin_amdgcn_mfma_f32_16x16x32_bf16(a, b, acc[nf], 0, 0, 0);
    }
  }
  float* base = part + (size_t)kc * (BATCH * ODIM);
#pragma unroll
  for (int nf = 0; nf < 6; ++nf)
#pragma unroll
    for (int rr = 0; rr < 4; ++rr)
      base[(size_t)(m0 + lm * 4 + rr) * ODIM + nf * 16 + ln] = acc[nf][rr];
}

__global__ void k_fc_red(const float* __restrict__ part, const float* __restrict__ bfc,
                         float* __restrict__ dout, bf16* __restrict__ decb, int t) {
  int i = blockIdx.x * blockDim.x + threadIdx.x;
  if (i >= BATCH * ODIM) return;
  int m = i / ODIM, n = i - m * ODIM;
  float s = bfc[n];
#pragma unroll
  for (int kc = 0; kc < 16; ++kc) s += part[(size_t)kc * (BATCH * ODIM) + i];
  s = sigm(s);
  dout[(size_t)m * (TSTEPS * ODIM) + t * ODIM + n] = s;
  decb[m * PADX + n] = (bf16)s;
}

// ---------------- launch ----------------
extern "C" void kernel_launch(void* const* d_in, const int* in_sizes, int n_in,
                              void* d_out, int out_size, void* d_ws, size_t ws_size,
                              hipStream_t stream) {
  const float* input   = (const float*)d_in[0];
  const float* hiddens = (const float*)d_in[2];
  const float* W_ih0   = (const float*)d_in[3];
  const float* W_hh0   = (const float*)d_in[4];
  const float* b_ih0   = (const float*)d_in[5];
  const float* b_hh0   = (const float*)d_in[6];
  const float* W_ih1   = (const float*)d_in[7];
  const float* W_hh1   = (const float*)d_in[8];
  const float* b_ih1   = (const float*)d_in[9];
  const float* b_hh1   = (const float*)d_in[10];
  const float* W_fc    = (const float*)d_in[11];
  const float* b_fc    = (const float*)d_in[12];
  float* out = (float*)d_out;

  char* p = (char*)d_ws;
  auto take = [&](size_t n) { char* q = p; p += (n + 255) & ~(size_t)255; return q; };
  bf16* wih0b = (bf16*)take((size_t)3 * GRU_H * PADX * 2);
  bf16* whh0b = (bf16*)take((size_t)3 * GRU_H * GRU_H * 2);
  bf16* wih1b = (bf16*)take((size_t)3 * GRU_H * GRU_H * 2);
  bf16* whh1b = (bf16*)take((size_t)3 * GRU_H * GRU_H * 2);
  bf16* wfcb  = (bf16*)take((size_t)ODIM * GRU_H * 2);
  bf16* decb  = (bf16*)take((size_t)BATCH * PADX * 2);
  float* h0f[2], *h1f[2];
  bf16* h0b[2], *h1b[2];
  h0f[0] = (float*)take((size_t)BATCH * GRU_H * 4);
  h0f[1] = (float*)take((size_t)BATCH * GRU_H * 4);
  h1f[0] = (float*)take((size_t)BATCH * GRU_H * 4);
  h1f[1] = (float*)take((size_t)BATCH * GRU_H * 4);
  h0b[0] = (bf16*)take((size_t)BATCH * GRU_H * 2);
  h0b[1] = (bf16*)take((size_t)BATCH * GRU_H * 2);
  h1b[0] = (bf16*)take((size_t)BATCH * GRU_H * 2);
  h1b[1] = (bf16*)take((size_t)BATCH * GRU_H * 2);
  float* fcpart = (float*)take((size_t)16 * BATCH * ODIM * 4);

  // one-time (per launch) conversions
  k_cvt_pad<<<768, 256, 0, stream>>>(W_ih0, wih0b, 3 * GRU_H, ODIM, PADX);
  k_cvt<<<2048, 256, 0, stream>>>(W_hh0, whh0b, 3 * GRU_H * GRU_H);
  k_cvt<<<2048, 256, 0, stream>>>(W_ih1, wih1b, 3 * GRU_H * GRU_H);
  k_cvt<<<2048, 256, 0, stream>>>(W_hh1, whh1b, 3 * GRU_H * GRU_H);
  k_cvt<<<192, 256, 0, stream>>>(W_fc, wfcb, ODIM * GRU_H);
  k_cvt_pad<<<512, 256, 0, stream>>>(input, decb, BATCH, ODIM, PADX);
  k_init_h<<<2048, 256, 0, stream>>>(hiddens, h0f[0], h0b[0], BATCH * GRU_H);
  k_init_h<<<2048, 256, 0, stream>>>(hiddens + (size_t)BATCH * GRU_H, h1f[0], h1b[0], BATCH * GRU_H);

  int cur = 0;
  for (int t = 0; t < TSTEPS; ++t) {
    int nxt = cur ^ 1;
    k_gru<<<dim3(32, 8), 512, 0, stream>>>(decb, PADX, h0b[cur], wih0b, whh0b,
                                           b_ih0, b_hh0, h0f[cur], h0f[nxt], h0b[nxt]);
    k_gru<<<dim3(32, 8), 512, 0, stream>>>(h0b[nxt], GRU_H, h1b[cur], wih1b, whh1b,
                                           b_ih1, b_hh1, h1f[cur], h1f[nxt], h1b[nxt]);
    k_fc_part<<<dim3(16, 16), 256, 0, stream>>>(h1b[nxt], wfcb, fcpart);
    k_fc_red<<<384, 256, 0, stream>>>(fcpart, b_fc, out, decb, t);
    cur = nxt;
  }
}